// Round 1
// baseline (184.867 us; speedup 1.0000x reference)
//
#include <hip/hip_runtime.h>
#include <hip/hip_bf16.h>

// Problem constants: B=2, C=128, H=W=D=24, S=13824, NH=4, hd=32, pooled SKV=1728, G=8
#define SB 2
#define SC 128
#define SS 13824
#define SNH 4
#define SHD 32
#define SKV 1728
#define GN_N 221184.0f        // elems per (b,g) = 16*13824
#define QSCALE 0.25504771249f // (1/sqrt(32)) * log2(e)

typedef unsigned int uint;
typedef unsigned short ushort;
typedef __bf16 bf16x8 __attribute__((ext_vector_type(8)));
typedef float f32x16 __attribute__((ext_vector_type(16)));

__device__ inline ushort f2bf(float v){
  __hip_bfloat16 h = __float2bfloat16(v);
  return *reinterpret_cast<ushort*>(&h);
}
__device__ inline float bf2f(ushort u){
  union { ushort s[2]; float f; } x; x.s[0] = 0; x.s[1] = u; return x.f;
}
__device__ inline uint pk2(float a, float b){
  __hip_bfloat162 h = __float22bfloat162_rn(make_float2(a, b));
  return *reinterpret_cast<uint*>(&h);
}
__device__ inline bf16x8 ldg8(const ushort* p){
  union { uint4 q; bf16x8 b; } u;
  u.q = *reinterpret_cast<const uint4*>(p);
  return u.b;
}
__device__ inline f32x16 mfma32(bf16x8 a, bf16x8 b, f32x16 c){
  return __builtin_amdgcn_mfma_f32_32x32x16_bf16(a, b, c, 0, 0, 0);
}
// C/D layout of 32x32 MFMA: col = lane&31, row = (r&3) + 8*((r>>2)&1) + 4*(lane>>5) + 16*(r>>3)
__device__ inline int rowmap(int r, int hl){
  return (r & 3) + 8 * ((r >> 2) & 1) + 4 * hl + 16 * (r >> 3);
}

// ---------------- K1a: per-channel sums for GroupNorm stats ----------------
__global__ __launch_bounds__(256) void k_stats(const float* __restrict__ x, float* __restrict__ chsums){
  int bid = blockIdx.x;            // 256 blocks = (b, c)
  int b = bid >> 7, c = bid & 127;
  const float4* p = reinterpret_cast<const float4*>(x + (size_t)(b * 128 + c) * SS);
  float s = 0.f, q = 0.f;
  for (int i = threadIdx.x; i < SS / 4; i += 256){
    float4 v = p[i];
    s += v.x + v.y + v.z + v.w;
    q += v.x * v.x + v.y * v.y + v.z * v.z + v.w * v.w;
  }
  for (int off = 32; off; off >>= 1){ s += __shfl_down(s, off, 64); q += __shfl_down(q, off, 64); }
  __shared__ float ls[4][2];
  int w = threadIdx.x >> 6, lane = threadIdx.x & 63;
  if (lane == 0){ ls[w][0] = s; ls[w][1] = q; }
  __syncthreads();
  if (threadIdx.x == 0){
    float S = ls[0][0] + ls[1][0] + ls[2][0] + ls[3][0];
    float Q = ls[0][1] + ls[1][1] + ls[2][1] + ls[3][1];
    chsums[(b * 128 + c) * 2] = S;
    chsums[(b * 128 + c) * 2 + 1] = Q;
  }
}

// ---------------- K1b: fold GN into qkv weights; convert proj_w ----------------
__global__ __launch_bounds__(256) void k_params(const float* __restrict__ chsums,
                                                const float* __restrict__ gn_w, const float* __restrict__ gn_b,
                                                const float* __restrict__ qkv_w, const float* __restrict__ qkv_b,
                                                const float* __restrict__ proj_w,
                                                ushort* __restrict__ Wp, float* __restrict__ biasP,
                                                ushort* __restrict__ pw){
  int tid = blockIdx.x * 256 + threadIdx.x;
  if (tid < 768){
    int b = tid / 384, o = tid % 384;
    float mul = (o < 128) ? QSCALE : 1.0f; // fold softmax scale*log2e into q
    ushort* wrow = Wp + (size_t)(b * 384 + o) * 128;
    float acc = 0.f;
    for (int g = 0; g < 8; ++g){
      float S = 0.f, Q = 0.f;
      for (int ch = g * 16; ch < g * 16 + 16; ++ch){
        S += chsums[(b * 128 + ch) * 2];
        Q += chsums[(b * 128 + ch) * 2 + 1];
      }
      float mu = S * (1.0f / GN_N);
      float var = Q * (1.0f / GN_N) - mu * mu;
      float rs = rsqrtf(var + 1e-5f);
      for (int ci = 0; ci < 16; ++ci){
        int c = g * 16 + ci;
        float a = gn_w[c] * rs;
        float be = gn_b[c] - mu * a;
        float wv = qkv_w[o * 128 + c];
        acc += wv * be;
        wrow[c] = f2bf(wv * a * mul);
      }
    }
    biasP[b * 384 + o] = (qkv_b[o] + acc) * mul;
  } else if (tid < 896){
    int o = tid - 768;
    for (int c = 0; c < 128; ++c) pw[o * 128 + c] = f2bf(proj_w[o * 128 + c]);
  }
}

// ---------------- K2: QKV GEMM  qkvT[b][s][o] = sum_c Wp[b][o][c]*x[b][c][s] + biasP ----------------
__global__ __launch_bounds__(256) void k_qkv(const float* __restrict__ x, const ushort* __restrict__ Wp,
                                             const float* __restrict__ biasP, ushort* __restrict__ qkvT){
  int bid = blockIdx.x;                 // 432 = b*216 + st*2 + oh
  int oh = bid & 1;
  int st = (bid >> 1) % 108;
  int b  = bid / 216;
  int t = threadIdx.x, w = t >> 6, lane = t & 63, hl = lane >> 5, ln = lane & 31;
  int s0 = st * 128 + w * 32;
  int s = s0 + ln;
  const float* xb = x + (size_t)b * 128 * SS;
  // A fragments: rows = s (lane&31), k = c; gather 8 strided dwords per k-step (coalesced across lanes)
  bf16x8 afr[8];
  #pragma unroll
  for (int ks = 0; ks < 8; ++ks){
    int cb = ks * 16 + hl * 8;
    union { ushort us[8]; bf16x8 b8; } f;
    #pragma unroll
    for (int j = 0; j < 8; ++j)
      f.us[j] = f2bf(xb[(size_t)(cb + j) * SS + s]);
    afr[ks] = f.b8;
  }
  for (int ot = 0; ot < 6; ++ot){
    int o0 = oh * 192 + ot * 32;
    f32x16 acc = {};
    const ushort* wrow = Wp + (size_t)(b * 384 + o0 + ln) * 128 + hl * 8;
    #pragma unroll
    for (int ks = 0; ks < 8; ++ks)
      acc = mfma32(afr[ks], ldg8(wrow + ks * 16), acc);
    float bo = biasP[b * 384 + o0 + ln];
    #pragma unroll
    for (int r = 0; r < 16; ++r){
      int srow = s0 + rowmap(r, hl);
      qkvT[(size_t)(b * SS + srow) * 384 + o0 + ln] = f2bf(acc[r] + bo);
    }
  }
}

// ---------------- K3: 2x2x2 avg-pool of K,V; K->[m][d], V->transposed [d][m] ----------------
__global__ __launch_bounds__(256) void k_pool(const ushort* __restrict__ qkvT,
                                              ushort* __restrict__ kpo, ushort* __restrict__ vpo){
  int bid = blockIdx.x;          // 216 = b*108 + h*27 + mt
  int mt = bid % 27;
  int h  = (bid / 27) & 3;
  int b  = bid / 108;
  int m0 = mt * 64;
  int t = threadIdx.x;
  __shared__ ushort V[32][72];
  int d = t & 31, mg = t >> 5;
  const ushort* base = qkvT + (size_t)b * SS * 384;
  #pragma unroll
  for (int it = 0; it < 8; ++it){
    int ml = mg + it * 8;
    int m = m0 + ml;
    int h2 = m / 144; int rem = m - h2 * 144; int w2 = rem / 12; int d2 = rem - w2 * 12;
    int sb = h2 * 1152 + w2 * 48 + d2 * 2;
    float sk = 0.f, sv = 0.f;
    #pragma unroll
    for (int i = 0; i < 2; ++i)
      #pragma unroll
      for (int j = 0; j < 2; ++j)
        #pragma unroll
        for (int kk = 0; kk < 2; ++kk){
          const ushort* row = base + (size_t)(sb + i * 576 + j * 24 + kk) * 384 + h * 32 + d;
          sk += bf2f(row[128]);
          sv += bf2f(row[256]);
        }
    kpo[(size_t)(b * 4 + h) * SKV * 32 + (size_t)m * 32 + d] = f2bf(sk * 0.125f);
    V[d][ml] = f2bf(sv * 0.125f);
  }
  __syncthreads();
  int dr = t >> 3, mc = (t & 7) * 8;
  uint4 vv = *reinterpret_cast<const uint4*>(&V[dr][mc]);
  *reinterpret_cast<uint4*>(&vpo[(size_t)(b * 4 + h) * 32 * SKV + (size_t)dr * SKV + m0 + mc]) = vv;
}

// ---------------- K4: flash attention, swapped QK^T; 1 query column per lane ----------------
__global__ __launch_bounds__(256) void k_attn(const ushort* __restrict__ qkvT, const ushort* __restrict__ kp,
                                              const ushort* __restrict__ vpT, ushort* __restrict__ Ot){
  int bid = blockIdx.x;           // 864 = (b*4+h)*108 + st
  int st = bid % 108;
  int bh = bid / 108;
  int h = bh & 3, b = bh >> 2;
  int t = threadIdx.x, w = t >> 6, lane = t & 63, hl = lane >> 5, ln = lane & 31;
  int n = st * 128 + w * 32 + ln;
  const ushort* qb = qkvT + (size_t)(b * SS + n) * 384 + h * 32;
  bf16x8 qf0 = ldg8(qb + hl * 8);
  bf16x8 qf1 = ldg8(qb + 16 + hl * 8);
  const ushort* kpb = kp + (size_t)(b * 4 + h) * SKV * 32;
  const ushort* vpb = vpT + (size_t)(b * 4 + h) * 32 * SKV + (size_t)ln * SKV;
  f32x16 oacc = {};
  float mrun = -1e30f, lrun = 0.f;
  for (int m0 = 0; m0 < SKV; m0 += 32){
    f32x16 sfr = {};
    const ushort* krow = kpb + (size_t)(m0 + ln) * 32 + hl * 8;
    sfr = mfma32(ldg8(krow), qf0, sfr);
    sfr = mfma32(ldg8(krow + 16), qf1, sfr);
    // online softmax; state is per query-column = per lane (mirrored in lane^32)
    float tm = sfr[0];
    #pragma unroll
    for (int r = 1; r < 16; ++r) tm = fmaxf(tm, sfr[r]);
    tm = fmaxf(tm, __shfl_xor(tm, 32, 64));
    float mnew = fmaxf(mrun, tm);
    float fs = exp2f(mrun - mnew);
    float ps = 0.f;
    #pragma unroll
    for (int r = 0; r < 16; ++r){ float p = exp2f(sfr[r] - mnew); sfr[r] = p; ps += p; }
    ps += __shfl_xor(ps, 32, 64);
    lrun = lrun * fs + ps;
    mrun = mnew;
    #pragma unroll
    for (int r = 0; r < 16; ++r) oacc[r] *= fs;
    // pack P to bf16 pairs; build P^T B-fragments with 2 shuffles per K=16 step
    uint P[8];
    #pragma unroll
    for (int i = 0; i < 8; ++i) P[i] = pk2(sfr[2 * i], sfr[2 * i + 1]);
    #pragma unroll
    for (int km = 0; km < 2; ++km){
      uint v1 = hl ? P[4 * km + 0] : P[4 * km + 2];
      uint v2 = hl ? P[4 * km + 1] : P[4 * km + 3];
      uint r1 = __shfl_xor(v1, 32, 64);
      uint r2 = __shfl_xor(v2, 32, 64);
      union { uint u[4]; bf16x8 b8; } pf;
      pf.u[0] = hl ? r1 : P[4 * km + 0];
      pf.u[1] = hl ? r2 : P[4 * km + 1];
      pf.u[2] = hl ? P[4 * km + 2] : r1;
      pf.u[3] = hl ? P[4 * km + 3] : r2;
      bf16x8 vf = ldg8(vpb + m0 + km * 16 + hl * 8);
      oacc = mfma32(vf, pf.b8, oacc);
    }
  }
  float inv = 1.f / lrun;
  // transpose O fragment (rows=d, cols=n) -> Ot[s][c] via per-wave LDS tile
  __shared__ ushort T[4][32 * 40];
  ushort* Tw = T[w];
  #pragma unroll
  for (int r = 0; r < 16; ++r){
    int d = rowmap(r, hl);
    Tw[ln * 40 + d] = f2bf(oacc[r] * inv);
  }
  __syncthreads();
  #pragma unroll
  for (int it = 0; it < 2; ++it){
    int d0 = hl * 8 + it * 16;
    uint4 vv = *reinterpret_cast<const uint4*>(&Tw[ln * 40 + d0]);
    *reinterpret_cast<uint4*>(&Ot[(size_t)(b * SS + n) * 128 + h * 32 + d0]) = vv;
  }
}

// ---------------- K5: proj GEMM + bias + residual ----------------
__global__ __launch_bounds__(256) void k_proj(const ushort* __restrict__ Ot, const ushort* __restrict__ pw,
                                              const float* __restrict__ pb, const float* __restrict__ xres,
                                              float* __restrict__ out){
  int bid = blockIdx.x;          // 216 = b*108 + st
  int st = bid % 108;
  int b = bid / 108;
  int t = threadIdx.x, w = t >> 6, lane = t & 63, hl = lane >> 5, ln = lane & 31;
  int s0 = st * 128 + w * 32;
  int s = s0 + ln;
  const ushort* ob = Ot + (size_t)(b * SS + s) * 128 + hl * 8;
  bf16x8 bfr[8];
  #pragma unroll
  for (int ks = 0; ks < 8; ++ks) bfr[ks] = ldg8(ob + ks * 16);
  for (int ot = 0; ot < 4; ++ot){
    f32x16 acc = {};
    const ushort* arow = pw + (size_t)(ot * 32 + ln) * 128 + hl * 8;
    #pragma unroll
    for (int ks = 0; ks < 8; ++ks)
      acc = mfma32(ldg8(arow + ks * 16), bfr[ks], acc);
    #pragma unroll
    for (int r = 0; r < 16; ++r){
      int o = ot * 32 + rowmap(r, hl);
      size_t idx = (size_t)(b * 128 + o) * SS + s;
      out[idx] = acc[r] + pb[o] + xres[idx];
    }
  }
}

extern "C" void kernel_launch(void* const* d_in, const int* in_sizes, int n_in,
                              void* d_out, int out_size, void* d_ws, size_t ws_size,
                              hipStream_t stream){
  const float* x      = (const float*)d_in[0];
  const float* gn_w   = (const float*)d_in[1];
  const float* gn_b   = (const float*)d_in[2];
  const float* qkv_w  = (const float*)d_in[3];
  const float* qkv_b  = (const float*)d_in[4];
  const float* proj_w = (const float*)d_in[5];
  const float* proj_b = (const float*)d_in[6];
  float* out = (float*)d_out;
  char* ws = (char*)d_ws;

  float*  chsums = (float*) (ws + 0);          // 2048 B
  ushort* Wp     = (ushort*)(ws + 2048);       // 196608 B
  float*  biasP  = (float*) (ws + 198656);     // 3072 B
  ushort* pw     = (ushort*)(ws + 201728);     // 32768 B
  ushort* qkvT   = (ushort*)(ws + 234496);     // 21233664 B
  ushort* kp     = (ushort*)(ws + 21468160);   // 884736 B
  ushort* vpT    = (ushort*)(ws + 22352896);   // 884736 B
  ushort* Ot     = (ushort*)(ws + 23237632);   // 7077888 B  (total ~30.3 MB)

  k_stats <<<256, 256, 0, stream>>>(x, chsums);
  k_params<<<4,   256, 0, stream>>>(chsums, gn_w, gn_b, qkv_w, qkv_b, proj_w, Wp, biasP, pw);
  k_qkv   <<<432, 256, 0, stream>>>(x, Wp, biasP, qkvT);
  k_pool  <<<216, 256, 0, stream>>>(qkvT, kp, vpT);
  k_attn  <<<864, 256, 0, stream>>>(qkvT, kp, vpT, Ot);
  k_proj  <<<216, 256, 0, stream>>>(Ot, pw, proj_b, x, out);
}

// Round 2
// 146.364 us; speedup vs baseline: 1.2631x; 1.2631x over previous
//
#include <hip/hip_runtime.h>
#include <hip/hip_bf16.h>

// Problem constants: B=2, C=128, H=W=D=24, S=13824, NH=4, hd=32, pooled SKV=1728, G=8
#define SB 2
#define SC 128
#define SS 13824
#define SNH 4
#define SHD 32
#define SKV 1728
#define GN_N 221184.0f        // elems per (b,g) = 16*13824
#define QSCALE 0.25504771249f // (1/sqrt(32)) * log2(e)

typedef unsigned int uint;
typedef unsigned short ushort;
typedef __bf16 bf16x8 __attribute__((ext_vector_type(8)));
typedef float f32x16 __attribute__((ext_vector_type(16)));

__device__ inline ushort f2bf(float v){
  __hip_bfloat16 h = __float2bfloat16(v);
  return *reinterpret_cast<ushort*>(&h);
}
__device__ inline float bf2f(ushort u){
  union { ushort s[2]; float f; } x; x.s[0] = 0; x.s[1] = u; return x.f;
}
__device__ inline uint pk2(float a, float b){
  __hip_bfloat162 h = __float22bfloat162_rn(make_float2(a, b));
  return *reinterpret_cast<uint*>(&h);
}
__device__ inline bf16x8 ldg8(const ushort* p){
  union { uint4 q; bf16x8 b; } u;
  u.q = *reinterpret_cast<const uint4*>(p);
  return u.b;
}
__device__ inline f32x16 mfma32(bf16x8 a, bf16x8 b, f32x16 c){
  return __builtin_amdgcn_mfma_f32_32x32x16_bf16(a, b, c, 0, 0, 0);
}
// C/D layout of 32x32 MFMA: col = lane&31, row = (r&3) + 8*((r>>2)&1) + 4*(lane>>5) + 16*(r>>3)
__device__ inline int rowmap(int r, int hl){
  return (r & 3) + 8 * ((r >> 2) & 1) + 4 * hl + 16 * (r >> 3);
}
__device__ inline float fexp2(float x){
#if __has_builtin(__builtin_amdgcn_exp2f)
  return __builtin_amdgcn_exp2f(x);
#else
  return exp2f(x);
#endif
}
__device__ inline float vmax16(const f32x16& v){
  float a0 = fmaxf(v[0], v[8]),  a1 = fmaxf(v[1], v[9]);
  float a2 = fmaxf(v[2], v[10]), a3 = fmaxf(v[3], v[11]);
  float a4 = fmaxf(v[4], v[12]), a5 = fmaxf(v[5], v[13]);
  float a6 = fmaxf(v[6], v[14]), a7 = fmaxf(v[7], v[15]);
  float b0 = fmaxf(a0, a4), b1 = fmaxf(a1, a5);
  float b2 = fmaxf(a2, a6), b3 = fmaxf(a3, a7);
  return fmaxf(fmaxf(b0, b1), fmaxf(b2, b3));
}
__device__ inline float vsum16(const f32x16& v){
  float a0 = v[0] + v[8],  a1 = v[1] + v[9];
  float a2 = v[2] + v[10], a3 = v[3] + v[11];
  float a4 = v[4] + v[12], a5 = v[5] + v[13];
  float a6 = v[6] + v[14], a7 = v[7] + v[15];
  float b0 = a0 + a4, b1 = a1 + a5, b2 = a2 + a6, b3 = a3 + a7;
  return (b0 + b1) + (b2 + b3);
}

// ---------------- K1a: per-channel sums for GroupNorm stats ----------------
__global__ __launch_bounds__(256) void k_stats(const float* __restrict__ x, float* __restrict__ chsums){
  int bid = blockIdx.x;            // 256 blocks = (b, c)
  int b = bid >> 7, c = bid & 127;
  const float4* p = reinterpret_cast<const float4*>(x + (size_t)(b * 128 + c) * SS);
  float s = 0.f, q = 0.f;
  for (int i = threadIdx.x; i < SS / 4; i += 256){
    float4 v = p[i];
    s += v.x + v.y + v.z + v.w;
    q += v.x * v.x + v.y * v.y + v.z * v.z + v.w * v.w;
  }
  for (int off = 32; off; off >>= 1){ s += __shfl_down(s, off, 64); q += __shfl_down(q, off, 64); }
  __shared__ float ls[4][2];
  int w = threadIdx.x >> 6, lane = threadIdx.x & 63;
  if (lane == 0){ ls[w][0] = s; ls[w][1] = q; }
  __syncthreads();
  if (threadIdx.x == 0){
    float S = ls[0][0] + ls[1][0] + ls[2][0] + ls[3][0];
    float Q = ls[0][1] + ls[1][1] + ls[2][1] + ls[3][1];
    chsums[(b * 128 + c) * 2] = S;
    chsums[(b * 128 + c) * 2 + 1] = Q;
  }
}

// ---------------- K1b: fold GN into qkv weights; convert proj_w ----------------
__global__ __launch_bounds__(256) void k_params(const float* __restrict__ chsums,
                                                const float* __restrict__ gn_w, const float* __restrict__ gn_b,
                                                const float* __restrict__ qkv_w, const float* __restrict__ qkv_b,
                                                const float* __restrict__ proj_w,
                                                ushort* __restrict__ Wp, float* __restrict__ biasP,
                                                ushort* __restrict__ pw){
  int tid = blockIdx.x * 256 + threadIdx.x;
  if (tid < 768){
    int b = tid / 384, o = tid % 384;
    float mul = (o < 128) ? QSCALE : 1.0f; // fold softmax scale*log2e into q
    ushort* wrow = Wp + (size_t)(b * 384 + o) * 128;
    float acc = 0.f;
    for (int g = 0; g < 8; ++g){
      float S = 0.f, Q = 0.f;
      for (int ch = g * 16; ch < g * 16 + 16; ++ch){
        S += chsums[(b * 128 + ch) * 2];
        Q += chsums[(b * 128 + ch) * 2 + 1];
      }
      float mu = S * (1.0f / GN_N);
      float var = Q * (1.0f / GN_N) - mu * mu;
      float rs = rsqrtf(var + 1e-5f);
      for (int ci = 0; ci < 16; ++ci){
        int c = g * 16 + ci;
        float a = gn_w[c] * rs;
        float be = gn_b[c] - mu * a;
        float wv = qkv_w[o * 128 + c];
        acc += wv * be;
        wrow[c] = f2bf(wv * a * mul);
      }
    }
    biasP[b * 384 + o] = (qkv_b[o] + acc) * mul;
  } else if (tid < 896){
    int o = tid - 768;
    for (int c = 0; c < 128; ++c) pw[o * 128 + c] = f2bf(proj_w[o * 128 + c]);
  }
}

// ---------------- K2: QKV GEMM  qkvT[b][s][o] = sum_c Wp[b][o][c]*x[b][c][s] + biasP ----------------
__global__ __launch_bounds__(256) void k_qkv(const float* __restrict__ x, const ushort* __restrict__ Wp,
                                             const float* __restrict__ biasP, ushort* __restrict__ qkvT){
  int bid = blockIdx.x;                 // 432 = b*216 + st*2 + oh
  int oh = bid & 1;
  int st = (bid >> 1) % 108;
  int b  = bid / 216;
  int t = threadIdx.x, w = t >> 6, lane = t & 63, hl = lane >> 5, ln = lane & 31;
  int s0 = st * 128 + w * 32;
  int s = s0 + ln;
  const float* xb = x + (size_t)b * 128 * SS;
  // A fragments: rows = s (lane&31), k = c; gather 8 strided dwords per k-step (coalesced across lanes)
  bf16x8 afr[8];
  #pragma unroll
  for (int ks = 0; ks < 8; ++ks){
    int cb = ks * 16 + hl * 8;
    union { ushort us[8]; bf16x8 b8; } f;
    #pragma unroll
    for (int j = 0; j < 8; ++j)
      f.us[j] = f2bf(xb[(size_t)(cb + j) * SS + s]);
    afr[ks] = f.b8;
  }
  for (int ot = 0; ot < 6; ++ot){
    int o0 = oh * 192 + ot * 32;
    f32x16 acc = {};
    const ushort* wrow = Wp + (size_t)(b * 384 + o0 + ln) * 128 + hl * 8;
    #pragma unroll
    for (int ks = 0; ks < 8; ++ks)
      acc = mfma32(afr[ks], ldg8(wrow + ks * 16), acc);
    float bo = biasP[b * 384 + o0 + ln];
    #pragma unroll
    for (int r = 0; r < 16; ++r){
      int srow = s0 + rowmap(r, hl);
      qkvT[(size_t)(b * SS + srow) * 384 + o0 + ln] = f2bf(acc[r] + bo);
    }
  }
}

// ---------------- K3: 2x2x2 avg-pool of K,V; K->[m][d], V->transposed [d][m] ----------------
__global__ __launch_bounds__(256) void k_pool(const ushort* __restrict__ qkvT,
                                              ushort* __restrict__ kpo, ushort* __restrict__ vpo){
  int bid = blockIdx.x;          // 216 = b*108 + h*27 + mt
  int mt = bid % 27;
  int h  = (bid / 27) & 3;
  int b  = bid / 108;
  int m0 = mt * 64;
  int t = threadIdx.x;
  __shared__ ushort V[32][72];
  int d = t & 31, mg = t >> 5;
  const ushort* base = qkvT + (size_t)b * SS * 384;
  #pragma unroll
  for (int it = 0; it < 8; ++it){
    int ml = mg + it * 8;
    int m = m0 + ml;
    int h2 = m / 144; int rem = m - h2 * 144; int w2 = rem / 12; int d2 = rem - w2 * 12;
    int sb = h2 * 1152 + w2 * 48 + d2 * 2;
    float sk = 0.f, sv = 0.f;
    #pragma unroll
    for (int i = 0; i < 2; ++i)
      #pragma unroll
      for (int j = 0; j < 2; ++j)
        #pragma unroll
        for (int kk = 0; kk < 2; ++kk){
          const ushort* row = base + (size_t)(sb + i * 576 + j * 24 + kk) * 384 + h * 32 + d;
          sk += bf2f(row[128]);
          sv += bf2f(row[256]);
        }
    kpo[(size_t)(b * 4 + h) * SKV * 32 + (size_t)m * 32 + d] = f2bf(sk * 0.125f);
    V[d][ml] = f2bf(sv * 0.125f);
  }
  __syncthreads();
  int dr = t >> 3, mc = (t & 7) * 8;
  uint4 vv = *reinterpret_cast<const uint4*>(&V[dr][mc]);
  *reinterpret_cast<uint4*>(&vpo[(size_t)(b * 4 + h) * 32 * SKV + (size_t)dr * SKV + m0 + mc]) = vv;
}

// ---------------- K4: flash attention, swapped QK^T; KVBLK=64, lean softmax ----------------
#define PVSTEP(Parr, i4, vf)                                         \
  {                                                                  \
    uint pa = hl ? Parr[(i4) + 0] : Parr[(i4) + 2];                  \
    uint pc = hl ? Parr[(i4) + 1] : Parr[(i4) + 3];                  \
    uint ra = __shfl_xor(pa, 32, 64);                                \
    uint rc = __shfl_xor(pc, 32, 64);                                \
    union { uint u[4]; bf16x8 b8; } pf;                              \
    pf.u[0] = hl ? ra : Parr[(i4) + 0];                              \
    pf.u[1] = hl ? rc : Parr[(i4) + 1];                              \
    pf.u[2] = hl ? Parr[(i4) + 2] : ra;                              \
    pf.u[3] = hl ? Parr[(i4) + 3] : rc;                              \
    oacc = mfma32(vf, pf.b8, oacc);                                  \
  }

__global__ __launch_bounds__(128, 4) void k_attn(const ushort* __restrict__ qkvT, const ushort* __restrict__ kp,
                                                 const ushort* __restrict__ vpT, ushort* __restrict__ Ot){
  int bid = blockIdx.x;           // 1728 = (b*4+h)*216 + st
  int st = bid % 216;
  int bh = bid / 216;
  int h = bh & 3, b = bh >> 2;
  int t = threadIdx.x, w = t >> 6, lane = t & 63, hl = lane >> 5, ln = lane & 31;
  int n = st * 64 + w * 32 + ln;
  const ushort* qb = qkvT + (size_t)(b * SS + n) * 384 + h * 32;
  bf16x8 qf0 = ldg8(qb + hl * 8);
  bf16x8 qf1 = ldg8(qb + 16 + hl * 8);
  const ushort* kpb = kp + (size_t)(b * 4 + h) * SKV * 32 + hl * 8;
  const ushort* vpb = vpT + (size_t)(b * 4 + h) * 32 * SKV + (size_t)ln * SKV + hl * 8;
  f32x16 oacc = {};
  float mrun = -1e30f, lrun = 0.f;
  for (int m0 = 0; m0 < SKV; m0 += 64){
    const ushort* ka = kpb + (size_t)(m0 + ln) * 32;
    bf16x8 ka0 = ldg8(ka), ka1 = ldg8(ka + 16);
    bf16x8 kb0 = ldg8(ka + 1024), kb1 = ldg8(ka + 1040);
    const ushort* vrow = vpb + m0;
    bf16x8 v0 = ldg8(vrow), v1 = ldg8(vrow + 16), v2 = ldg8(vrow + 32), v3 = ldg8(vrow + 48);
    f32x16 s0 = {}, s1 = {};
    s0 = mfma32(ka0, qf0, s0);
    s0 = mfma32(ka1, qf1, s0);
    s1 = mfma32(kb0, qf0, s1);
    s1 = mfma32(kb1, qf1, s1);
    // online softmax, state per query-column (mirrored in lane^32)
    float tm = fmaxf(vmax16(s0), vmax16(s1));
    tm = fmaxf(tm, __shfl_xor(tm, 32, 64));
    if (__any(tm > mrun)){            // exact: rescale only when running max grows
      float mnew = fmaxf(mrun, tm);
      float fs = fexp2(mrun - mnew);
      lrun *= fs;
      #pragma unroll
      for (int r = 0; r < 16; ++r) oacc[r] *= fs;
      mrun = mnew;
    }
    #pragma unroll
    for (int r = 0; r < 16; ++r) s0[r] = fexp2(s0[r] - mrun);
    #pragma unroll
    for (int r = 0; r < 16; ++r) s1[r] = fexp2(s1[r] - mrun);
    float ps = vsum16(s0) + vsum16(s1);
    ps += __shfl_xor(ps, 32, 64);
    lrun += ps;
    // pack P to bf16; build P^T B-fragments with 2 shuffles per K=16 step
    uint P0[8], P1[8];
    #pragma unroll
    for (int i = 0; i < 8; ++i) P0[i] = pk2(s0[2 * i], s0[2 * i + 1]);
    #pragma unroll
    for (int i = 0; i < 8; ++i) P1[i] = pk2(s1[2 * i], s1[2 * i + 1]);
    PVSTEP(P0, 0, v0)
    PVSTEP(P0, 4, v1)
    PVSTEP(P1, 0, v2)
    PVSTEP(P1, 4, v3)
  }
  float inv = 1.f / lrun;
  // transpose O fragment (rows=d, cols=n) -> Ot[s][c] via per-wave LDS tile
  __shared__ ushort T[2][32 * 40];
  ushort* Tw = T[w];
  #pragma unroll
  for (int r = 0; r < 16; ++r){
    int d = rowmap(r, hl);
    Tw[ln * 40 + d] = f2bf(oacc[r] * inv);
  }
  __syncthreads();
  #pragma unroll
  for (int it = 0; it < 2; ++it){
    int d0 = hl * 8 + it * 16;
    uint4 vv = *reinterpret_cast<const uint4*>(&Tw[ln * 40 + d0]);
    *reinterpret_cast<uint4*>(&Ot[(size_t)(b * SS + n) * 128 + h * 32 + d0]) = vv;
  }
}

// ---------------- K5: proj GEMM + bias + residual ----------------
__global__ __launch_bounds__(256) void k_proj(const ushort* __restrict__ Ot, const ushort* __restrict__ pw,
                                              const float* __restrict__ pb, const float* __restrict__ xres,
                                              float* __restrict__ out){
  int bid = blockIdx.x;          // 216 = b*108 + st
  int st = bid % 108;
  int b = bid / 108;
  int t = threadIdx.x, w = t >> 6, lane = t & 63, hl = lane >> 5, ln = lane & 31;
  int s0 = st * 128 + w * 32;
  int s = s0 + ln;
  const ushort* ob = Ot + (size_t)(b * SS + s) * 128 + hl * 8;
  bf16x8 bfr[8];
  #pragma unroll
  for (int ks = 0; ks < 8; ++ks) bfr[ks] = ldg8(ob + ks * 16);
  for (int ot = 0; ot < 4; ++ot){
    f32x16 acc = {};
    const ushort* arow = pw + (size_t)(ot * 32 + ln) * 128 + hl * 8;
    #pragma unroll
    for (int ks = 0; ks < 8; ++ks)
      acc = mfma32(ldg8(arow + ks * 16), bfr[ks], acc);
    #pragma unroll
    for (int r = 0; r < 16; ++r){
      int o = ot * 32 + rowmap(r, hl);
      size_t idx = (size_t)(b * 128 + o) * SS + s;
      out[idx] = acc[r] + pb[o] + xres[idx];
    }
  }
}

extern "C" void kernel_launch(void* const* d_in, const int* in_sizes, int n_in,
                              void* d_out, int out_size, void* d_ws, size_t ws_size,
                              hipStream_t stream){
  const float* x      = (const float*)d_in[0];
  const float* gn_w   = (const float*)d_in[1];
  const float* gn_b   = (const float*)d_in[2];
  const float* qkv_w  = (const float*)d_in[3];
  const float* qkv_b  = (const float*)d_in[4];
  const float* proj_w = (const float*)d_in[5];
  const float* proj_b = (const float*)d_in[6];
  float* out = (float*)d_out;
  char* ws = (char*)d_ws;

  float*  chsums = (float*) (ws + 0);          // 2048 B
  ushort* Wp     = (ushort*)(ws + 2048);       // 196608 B
  float*  biasP  = (float*) (ws + 198656);     // 3072 B
  ushort* pw     = (ushort*)(ws + 201728);     // 32768 B
  ushort* qkvT   = (ushort*)(ws + 234496);     // 21233664 B
  ushort* kp     = (ushort*)(ws + 21468160);   // 884736 B
  ushort* vpT    = (ushort*)(ws + 22352896);   // 884736 B
  ushort* Ot     = (ushort*)(ws + 23237632);   // 7077888 B  (total ~30.3 MB)

  k_stats <<<256,  256, 0, stream>>>(x, chsums);
  k_params<<<4,    256, 0, stream>>>(chsums, gn_w, gn_b, qkv_w, qkv_b, proj_w, Wp, biasP, pw);
  k_qkv   <<<432,  256, 0, stream>>>(x, Wp, biasP, qkvT);
  k_pool  <<<216,  256, 0, stream>>>(qkvT, kp, vpT);
  k_attn  <<<1728, 128, 0, stream>>>(qkvT, kp, vpT, Ot);
  k_proj  <<<216,  256, 0, stream>>>(Ot, pw, proj_b, x, out);
}

// Round 3
// 143.672 us; speedup vs baseline: 1.2867x; 1.0187x over previous
//
#include <hip/hip_runtime.h>
#include <hip/hip_bf16.h>

// Problem constants: B=2, C=128, H=W=D=24, S=13824, NH=4, hd=32, pooled SKV=1728, G=8
#define SB 2
#define SC 128
#define SS 13824
#define SNH 4
#define SHD 32
#define SKV 1728
#define GN_N 221184.0f        // elems per (b,g) = 16*13824
#define QSCALE 0.25504771249f // (1/sqrt(32)) * log2(e)

typedef unsigned int uint;
typedef unsigned short ushort;
typedef __bf16 bf16x8 __attribute__((ext_vector_type(8)));
typedef float f32x16 __attribute__((ext_vector_type(16)));

__device__ inline ushort f2bf(float v){
  __hip_bfloat16 h = __float2bfloat16(v);
  return *reinterpret_cast<ushort*>(&h);
}
__device__ inline float bf2f(ushort u){
  union { ushort s[2]; float f; } x; x.s[0] = 0; x.s[1] = u; return x.f;
}
__device__ inline uint pk2(float a, float b){
  __hip_bfloat162 h = __float22bfloat162_rn(make_float2(a, b));
  return *reinterpret_cast<uint*>(&h);
}
__device__ inline bf16x8 ldg8(const ushort* p){
  union { uint4 q; bf16x8 b; } u;
  u.q = *reinterpret_cast<const uint4*>(p);
  return u.b;
}
__device__ inline f32x16 mfma32(bf16x8 a, bf16x8 b, f32x16 c){
  return __builtin_amdgcn_mfma_f32_32x32x16_bf16(a, b, c, 0, 0, 0);
}
// C/D layout of 32x32 MFMA: col = lane&31, row = (r&3) + 8*((r>>2)&1) + 4*(lane>>5) + 16*(r>>3)
__device__ inline int rowmap(int r, int hl){
  return (r & 3) + 8 * ((r >> 2) & 1) + 4 * hl + 16 * (r >> 3);
}
__device__ inline float fexp2(float x){
#if __has_builtin(__builtin_amdgcn_exp2f)
  return __builtin_amdgcn_exp2f(x);
#else
  return exp2f(x);
#endif
}

// ---------------- K1a: per-channel sums for GroupNorm stats ----------------
__global__ __launch_bounds__(256) void k_stats(const float* __restrict__ x, float* __restrict__ chsums){
  int bid = blockIdx.x;            // 256 blocks = (b, c)
  int b = bid >> 7, c = bid & 127;
  const float4* p = reinterpret_cast<const float4*>(x + (size_t)(b * 128 + c) * SS);
  float s = 0.f, q = 0.f;
  for (int i = threadIdx.x; i < SS / 4; i += 256){
    float4 v = p[i];
    s += v.x + v.y + v.z + v.w;
    q += v.x * v.x + v.y * v.y + v.z * v.z + v.w * v.w;
  }
  for (int off = 32; off; off >>= 1){ s += __shfl_down(s, off, 64); q += __shfl_down(q, off, 64); }
  __shared__ float ls[4][2];
  int w = threadIdx.x >> 6, lane = threadIdx.x & 63;
  if (lane == 0){ ls[w][0] = s; ls[w][1] = q; }
  __syncthreads();
  if (threadIdx.x == 0){
    float S = ls[0][0] + ls[1][0] + ls[2][0] + ls[3][0];
    float Q = ls[0][1] + ls[1][1] + ls[2][1] + ls[3][1];
    chsums[(b * 128 + c) * 2] = S;
    chsums[(b * 128 + c) * 2 + 1] = Q;
  }
}

// ---------------- K1b: fold GN into qkv weights; convert proj_w ----------------
__global__ __launch_bounds__(256) void k_params(const float* __restrict__ chsums,
                                                const float* __restrict__ gn_w, const float* __restrict__ gn_b,
                                                const float* __restrict__ qkv_w, const float* __restrict__ qkv_b,
                                                const float* __restrict__ proj_w,
                                                ushort* __restrict__ Wp, float* __restrict__ biasP,
                                                ushort* __restrict__ pw){
  int tid = blockIdx.x * 256 + threadIdx.x;
  if (tid < 768){
    int b = tid / 384, o = tid % 384;
    float mul = (o < 128) ? QSCALE : 1.0f; // fold softmax scale*log2e into q
    ushort* wrow = Wp + (size_t)(b * 384 + o) * 128;
    float acc = 0.f;
    for (int g = 0; g < 8; ++g){
      float S = 0.f, Q = 0.f;
      for (int ch = g * 16; ch < g * 16 + 16; ++ch){
        S += chsums[(b * 128 + ch) * 2];
        Q += chsums[(b * 128 + ch) * 2 + 1];
      }
      float mu = S * (1.0f / GN_N);
      float var = Q * (1.0f / GN_N) - mu * mu;
      float rs = rsqrtf(var + 1e-5f);
      for (int ci = 0; ci < 16; ++ci){
        int c = g * 16 + ci;
        float a = gn_w[c] * rs;
        float be = gn_b[c] - mu * a;
        float wv = qkv_w[o * 128 + c];
        acc += wv * be;
        wrow[c] = f2bf(wv * a * mul);
      }
    }
    biasP[b * 384 + o] = (qkv_b[o] + acc) * mul;
  } else if (tid < 896){
    int o = tid - 768;
    for (int c = 0; c < 128; ++c) pw[o * 128 + c] = f2bf(proj_w[o * 128 + c]);
  }
}

// ---------------- K2: QKV GEMM  qkvT[b][s][o] = sum_c Wp[b][o][c]*x[b][c][s] + biasP ----------------
__global__ __launch_bounds__(256) void k_qkv(const float* __restrict__ x, const ushort* __restrict__ Wp,
                                             const float* __restrict__ biasP, ushort* __restrict__ qkvT){
  int bid = blockIdx.x;                 // 432 = b*216 + st*2 + oh
  int oh = bid & 1;
  int st = (bid >> 1) % 108;
  int b  = bid / 216;
  int t = threadIdx.x, w = t >> 6, lane = t & 63, hl = lane >> 5, ln = lane & 31;
  int s0 = st * 128 + w * 32;
  int s = s0 + ln;
  const float* xb = x + (size_t)b * 128 * SS;
  // A fragments: rows = s (lane&31), k = c; gather 8 strided dwords per k-step (coalesced across lanes)
  bf16x8 afr[8];
  #pragma unroll
  for (int ks = 0; ks < 8; ++ks){
    int cb = ks * 16 + hl * 8;
    union { ushort us[8]; bf16x8 b8; } f;
    #pragma unroll
    for (int j = 0; j < 8; ++j)
      f.us[j] = f2bf(xb[(size_t)(cb + j) * SS + s]);
    afr[ks] = f.b8;
  }
  for (int ot = 0; ot < 6; ++ot){
    int o0 = oh * 192 + ot * 32;
    f32x16 acc = {};
    const ushort* wrow = Wp + (size_t)(b * 384 + o0 + ln) * 128 + hl * 8;
    #pragma unroll
    for (int ks = 0; ks < 8; ++ks)
      acc = mfma32(afr[ks], ldg8(wrow + ks * 16), acc);
    float bo = biasP[b * 384 + o0 + ln];
    #pragma unroll
    for (int r = 0; r < 16; ++r){
      int srow = s0 + rowmap(r, hl);
      qkvT[(size_t)(b * SS + srow) * 384 + o0 + ln] = f2bf(acc[r] + bo);
    }
  }
}

// ---------------- K3: 2x2x2 avg-pool of K,V; K->[m][d], V->transposed [d][m] ----------------
__global__ __launch_bounds__(256) void k_pool(const ushort* __restrict__ qkvT,
                                              ushort* __restrict__ kpo, ushort* __restrict__ vpo){
  int bid = blockIdx.x;          // 216 = b*108 + h*27 + mt
  int mt = bid % 27;
  int h  = (bid / 27) & 3;
  int b  = bid / 108;
  int m0 = mt * 64;
  int t = threadIdx.x;
  __shared__ ushort V[32][72];
  int d = t & 31, mg = t >> 5;
  const ushort* base = qkvT + (size_t)b * SS * 384;
  #pragma unroll
  for (int it = 0; it < 8; ++it){
    int ml = mg + it * 8;
    int m = m0 + ml;
    int h2 = m / 144; int rem = m - h2 * 144; int w2 = rem / 12; int d2 = rem - w2 * 12;
    int sb = h2 * 1152 + w2 * 48 + d2 * 2;
    float sk = 0.f, sv = 0.f;
    #pragma unroll
    for (int i = 0; i < 2; ++i)
      #pragma unroll
      for (int j = 0; j < 2; ++j)
        #pragma unroll
        for (int kk = 0; kk < 2; ++kk){
          const ushort* row = base + (size_t)(sb + i * 576 + j * 24 + kk) * 384 + h * 32 + d;
          sk += bf2f(row[128]);
          sv += bf2f(row[256]);
        }
    kpo[(size_t)(b * 4 + h) * SKV * 32 + (size_t)m * 32 + d] = f2bf(sk * 0.125f);
    V[d][ml] = f2bf(sv * 0.125f);
  }
  __syncthreads();
  int dr = t >> 3, mc = (t & 7) * 8;
  uint4 vv = *reinterpret_cast<const uint4*>(&V[dr][mc]);
  *reinterpret_cast<uint4*>(&vpo[(size_t)(b * 4 + h) * 32 * SKV + (size_t)dr * SKV + m0 + mc]) = vv;
}

// ---------------- K4: attention, stateless softmax (no online max: |scores| <~ 3),
// l via ones-row MFMA, P cross-half exchange via v_permlane32_swap_b32,
// K double-buffered in registers ----------------
#define PVSTEP(Parr, i4, vf)                                         \
  {                                                                  \
    uint a0 = Parr[(i4) + 0], a1 = Parr[(i4) + 1];                   \
    uint b0 = Parr[(i4) + 2], b1 = Parr[(i4) + 3];                   \
    asm("v_permlane32_swap_b32 %0, %1" : "+v"(a0), "+v"(b0));        \
    asm("v_permlane32_swap_b32 %0, %1" : "+v"(a1), "+v"(b1));        \
    union { uint u[4]; bf16x8 b8; } pf;                              \
    pf.u[0] = a0; pf.u[1] = a1; pf.u[2] = b0; pf.u[3] = b1;          \
    oacc = mfma32(vf, pf.b8, oacc);                                  \
    lacc = mfma32(ones, pf.b8, lacc);                                \
  }

__global__ __launch_bounds__(128, 4) void k_attn(const ushort* __restrict__ qkvT, const ushort* __restrict__ kp,
                                                 const ushort* __restrict__ vpT, ushort* __restrict__ Ot){
  int bid = blockIdx.x;           // 1728 = (b*4+h)*216 + st
  int st = bid % 216;
  int bh = bid / 216;
  int h = bh & 3, b = bh >> 2;
  int t = threadIdx.x, w = t >> 6, lane = t & 63, hl = lane >> 5, ln = lane & 31;
  int n = st * 64 + w * 32 + ln;
  const ushort* qb = qkvT + (size_t)(b * SS + n) * 384 + h * 32;
  bf16x8 qf0 = ldg8(qb + hl * 8);
  bf16x8 qf1 = ldg8(qb + 16 + hl * 8);
  const ushort* kpb = kp + (size_t)(b * 4 + h) * SKV * 32 + (size_t)ln * 32 + hl * 8;
  const ushort* vpb = vpT + (size_t)(b * 4 + h) * 32 * SKV + (size_t)ln * SKV + hl * 8;
  union { ushort us[8]; bf16x8 b8; } one8;
  #pragma unroll
  for (int j = 0; j < 8; ++j) one8.us[j] = 0x3F80; // bf16 1.0
  bf16x8 ones = one8.b8;
  f32x16 oacc = {}, lacc = {};
  // preload K tile 0 (keys 0..63)
  bf16x8 kc0 = ldg8(kpb), kc1 = ldg8(kpb + 16);
  bf16x8 kc2 = ldg8(kpb + 1024), kc3 = ldg8(kpb + 1040);
  for (int m0 = 0; m0 < SKV; m0 += 64){
    // V of current tile: issued ~150cy before PV use
    const ushort* vrow = vpb + m0;
    bf16x8 v0 = ldg8(vrow), v1 = ldg8(vrow + 16), v2 = ldg8(vrow + 32), v3 = ldg8(vrow + 48);
    // QK^T on current K
    f32x16 s0 = {}, s1 = {};
    s0 = mfma32(kc0, qf0, s0);
    s0 = mfma32(kc1, qf1, s0);
    s1 = mfma32(kc2, qf0, s1);
    s1 = mfma32(kc3, qf1, s1);
    // prefetch next K tile (wrap to 0 on last iter to keep addresses valid)
    int mn = m0 + 64; if (mn == SKV) mn = 0;
    const ushort* ka = kpb + (size_t)mn * 32;
    bf16x8 kn0 = ldg8(ka), kn1 = ldg8(ka + 16);
    bf16x8 kn2 = ldg8(ka + 1024), kn3 = ldg8(ka + 1040);
    // stateless softmax numerator: P = exp2(s) (scale*log2e folded into q)
    #pragma unroll
    for (int r = 0; r < 16; ++r) s0[r] = fexp2(s0[r]);
    #pragma unroll
    for (int r = 0; r < 16; ++r) s1[r] = fexp2(s1[r]);
    uint P0[8], P1[8];
    #pragma unroll
    for (int i = 0; i < 8; ++i) P0[i] = pk2(s0[2 * i], s0[2 * i + 1]);
    #pragma unroll
    for (int i = 0; i < 8; ++i) P1[i] = pk2(s1[2 * i], s1[2 * i + 1]);
    PVSTEP(P0, 0, v0)
    PVSTEP(P0, 4, v1)
    PVSTEP(P1, 0, v2)
    PVSTEP(P1, 4, v3)
    kc0 = kn0; kc1 = kn1; kc2 = kn2; kc3 = kn3;
  }
  float inv = 1.f / lacc[0];   // lacc rows all hold sum_k P[k][col]
  // transpose O fragment (rows=d, cols=n) -> Ot[s][c] via per-wave LDS tile
  __shared__ ushort T[2][32 * 40];
  ushort* Tw = T[w];
  #pragma unroll
  for (int r = 0; r < 16; ++r){
    int d = rowmap(r, hl);
    Tw[ln * 40 + d] = f2bf(oacc[r] * inv);
  }
  __syncthreads();
  #pragma unroll
  for (int it = 0; it < 2; ++it){
    int d0 = hl * 8 + it * 16;
    uint4 vv = *reinterpret_cast<const uint4*>(&Tw[ln * 40 + d0]);
    *reinterpret_cast<uint4*>(&Ot[(size_t)(b * SS + n) * 128 + h * 32 + d0]) = vv;
  }
}

// ---------------- K5: proj GEMM + bias + residual ----------------
__global__ __launch_bounds__(256) void k_proj(const ushort* __restrict__ Ot, const ushort* __restrict__ pw,
                                              const float* __restrict__ pb, const float* __restrict__ xres,
                                              float* __restrict__ out){
  int bid = blockIdx.x;          // 216 = b*108 + st
  int st = bid % 108;
  int b = bid / 108;
  int t = threadIdx.x, w = t >> 6, lane = t & 63, hl = lane >> 5, ln = lane & 31;
  int s0 = st * 128 + w * 32;
  int s = s0 + ln;
  const ushort* ob = Ot + (size_t)(b * SS + s) * 128 + hl * 8;
  bf16x8 bfr[8];
  #pragma unroll
  for (int ks = 0; ks < 8; ++ks) bfr[ks] = ldg8(ob + ks * 16);
  for (int ot = 0; ot < 4; ++ot){
    f32x16 acc = {};
    const ushort* arow = pw + (size_t)(ot * 32 + ln) * 128 + hl * 8;
    #pragma unroll
    for (int ks = 0; ks < 8; ++ks)
      acc = mfma32(ldg8(arow + ks * 16), bfr[ks], acc);
    #pragma unroll
    for (int r = 0; r < 16; ++r){
      int o = ot * 32 + rowmap(r, hl);
      size_t idx = (size_t)(b * 128 + o) * SS + s;
      out[idx] = acc[r] + pb[o] + xres[idx];
    }
  }
}

extern "C" void kernel_launch(void* const* d_in, const int* in_sizes, int n_in,
                              void* d_out, int out_size, void* d_ws, size_t ws_size,
                              hipStream_t stream){
  const float* x      = (const float*)d_in[0];
  const float* gn_w   = (const float*)d_in[1];
  const float* gn_b   = (const float*)d_in[2];
  const float* qkv_w  = (const float*)d_in[3];
  const float* qkv_b  = (const float*)d_in[4];
  const float* proj_w = (const float*)d_in[5];
  const float* proj_b = (const float*)d_in[6];
  float* out = (float*)d_out;
  char* ws = (char*)d_ws;

  float*  chsums = (float*) (ws + 0);          // 2048 B
  ushort* Wp     = (ushort*)(ws + 2048);       // 196608 B
  float*  biasP  = (float*) (ws + 198656);     // 3072 B
  ushort* pw     = (ushort*)(ws + 201728);     // 32768 B
  ushort* qkvT   = (ushort*)(ws + 234496);     // 21233664 B
  ushort* kp     = (ushort*)(ws + 21468160);   // 884736 B
  ushort* vpT    = (ushort*)(ws + 22352896);   // 884736 B
  ushort* Ot     = (ushort*)(ws + 23237632);   // 7077888 B  (total ~30.3 MB)

  k_stats <<<256,  256, 0, stream>>>(x, chsums);
  k_params<<<4,    256, 0, stream>>>(chsums, gn_w, gn_b, qkv_w, qkv_b, proj_w, Wp, biasP, pw);
  k_qkv   <<<432,  256, 0, stream>>>(x, Wp, biasP, qkvT);
  k_pool  <<<216,  256, 0, stream>>>(qkvT, kp, vpT);
  k_attn  <<<1728, 128, 0, stream>>>(qkvT, kp, vpT, Ot);
  k_proj  <<<216,  256, 0, stream>>>(Ot, pw, proj_b, x, out);
}

// Round 4
// 121.051 us; speedup vs baseline: 1.5272x; 1.1869x over previous
//
#include <hip/hip_runtime.h>
#include <hip/hip_bf16.h>

// Problem constants: B=2, C=128, H=W=D=24, S=13824, NH=4, hd=32, pooled SKV=1728, G=8
#define SB 2
#define SC 128
#define SS 13824
#define SNH 4
#define SHD 32
#define SKV 1728
#define GN_N 221184.0f        // elems per (b,g) = 16*13824
#define QSCALE 0.25504771249f // (1/sqrt(32)) * log2(e)

typedef unsigned int uint;
typedef unsigned short ushort;
typedef __bf16 bf16x8 __attribute__((ext_vector_type(8)));
typedef float f32x16 __attribute__((ext_vector_type(16)));

__device__ inline ushort f2bf(float v){
  __hip_bfloat16 h = __float2bfloat16(v);
  return *reinterpret_cast<ushort*>(&h);
}
__device__ inline float bf2f(ushort u){
  union { ushort s[2]; float f; } x; x.s[0] = 0; x.s[1] = u; return x.f;
}
__device__ inline uint pk2(float a, float b){
  __hip_bfloat162 h = __float22bfloat162_rn(make_float2(a, b));
  return *reinterpret_cast<uint*>(&h);
}
__device__ inline bf16x8 ldg8(const ushort* p){
  union { uint4 q; bf16x8 b; } u;
  u.q = *reinterpret_cast<const uint4*>(p);
  return u.b;
}
__device__ inline f32x16 mfma32(bf16x8 a, bf16x8 b, f32x16 c){
  return __builtin_amdgcn_mfma_f32_32x32x16_bf16(a, b, c, 0, 0, 0);
}
// C/D layout of 32x32 MFMA: col = lane&31, row = (r&3) + 8*((r>>2)&1) + 4*(lane>>5) + 16*(r>>3)
__device__ inline int rowmap(int r, int hl){
  return (r & 3) + 8 * ((r >> 2) & 1) + 4 * hl + 16 * (r >> 3);
}
__device__ inline float fexp2(float x){
#if __has_builtin(__builtin_amdgcn_exp2f)
  return __builtin_amdgcn_exp2f(x);
#else
  return exp2f(x);
#endif
}

// ---------------- K1a: per-channel sums for GroupNorm stats ----------------
__global__ __launch_bounds__(256) void k_stats(const float* __restrict__ x, float* __restrict__ chsums){
  int bid = blockIdx.x;            // 256 blocks = (b, c)
  int b = bid >> 7, c = bid & 127;
  const float4* p = reinterpret_cast<const float4*>(x + (size_t)(b * 128 + c) * SS);
  float s = 0.f, q = 0.f;
  for (int i = threadIdx.x; i < SS / 4; i += 256){
    float4 v = p[i];
    s += v.x + v.y + v.z + v.w;
    q += v.x * v.x + v.y * v.y + v.z * v.z + v.w * v.w;
  }
  for (int off = 32; off; off >>= 1){ s += __shfl_down(s, off, 64); q += __shfl_down(q, off, 64); }
  __shared__ float ls[4][2];
  int w = threadIdx.x >> 6, lane = threadIdx.x & 63;
  if (lane == 0){ ls[w][0] = s; ls[w][1] = q; }
  __syncthreads();
  if (threadIdx.x == 0){
    float S = ls[0][0] + ls[1][0] + ls[2][0] + ls[3][0];
    float Q = ls[0][1] + ls[1][1] + ls[2][1] + ls[3][1];
    chsums[(b * 128 + c) * 2] = S;
    chsums[(b * 128 + c) * 2 + 1] = Q;
  }
}

// ---------------- K1b: fold GN into qkv weights; convert proj_w ----------------
__global__ __launch_bounds__(256) void k_params(const float* __restrict__ chsums,
                                                const float* __restrict__ gn_w, const float* __restrict__ gn_b,
                                                const float* __restrict__ qkv_w, const float* __restrict__ qkv_b,
                                                const float* __restrict__ proj_w,
                                                ushort* __restrict__ Wp, float* __restrict__ biasP,
                                                ushort* __restrict__ pw){
  int tid = blockIdx.x * 256 + threadIdx.x;
  if (tid < 768){
    int b = tid / 384, o = tid % 384;
    float mul = (o < 128) ? QSCALE : 1.0f; // fold softmax scale*log2e into q
    ushort* wrow = Wp + (size_t)(b * 384 + o) * 128;
    float acc = 0.f;
    for (int g = 0; g < 8; ++g){
      float S = 0.f, Q = 0.f;
      for (int ch = g * 16; ch < g * 16 + 16; ++ch){
        S += chsums[(b * 128 + ch) * 2];
        Q += chsums[(b * 128 + ch) * 2 + 1];
      }
      float mu = S * (1.0f / GN_N);
      float var = Q * (1.0f / GN_N) - mu * mu;
      float rs = rsqrtf(var + 1e-5f);
      for (int ci = 0; ci < 16; ++ci){
        int c = g * 16 + ci;
        float a = gn_w[c] * rs;
        float be = gn_b[c] - mu * a;
        float wv = qkv_w[o * 128 + c];
        acc += wv * be;
        wrow[c] = f2bf(wv * a * mul);
      }
    }
    biasP[b * 384 + o] = (qkv_b[o] + acc) * mul;
  } else if (tid < 896){
    int o = tid - 768;
    for (int c = 0; c < 128; ++c) pw[o * 128 + c] = f2bf(proj_w[o * 128 + c]);
  }
}

// ---------------- K2: QKV GEMM  qkvT[b][s][o] = sum_c Wp[b][o][c]*x[b][c][s] + biasP ----------------
__global__ __launch_bounds__(256) void k_qkv(const float* __restrict__ x, const ushort* __restrict__ Wp,
                                             const float* __restrict__ biasP, ushort* __restrict__ qkvT){
  int bid = blockIdx.x;                 // 432 = b*216 + st*2 + oh
  int oh = bid & 1;
  int st = (bid >> 1) % 108;
  int b  = bid / 216;
  int t = threadIdx.x, w = t >> 6, lane = t & 63, hl = lane >> 5, ln = lane & 31;
  int s0 = st * 128 + w * 32;
  int s = s0 + ln;
  const float* xb = x + (size_t)b * 128 * SS;
  // A fragments: rows = s (lane&31), k = c; gather 8 strided dwords per k-step (coalesced across lanes)
  bf16x8 afr[8];
  #pragma unroll
  for (int ks = 0; ks < 8; ++ks){
    int cb = ks * 16 + hl * 8;
    union { ushort us[8]; bf16x8 b8; } f;
    #pragma unroll
    for (int j = 0; j < 8; ++j)
      f.us[j] = f2bf(xb[(size_t)(cb + j) * SS + s]);
    afr[ks] = f.b8;
  }
  for (int ot = 0; ot < 6; ++ot){
    int o0 = oh * 192 + ot * 32;
    f32x16 acc = {};
    const ushort* wrow = Wp + (size_t)(b * 384 + o0 + ln) * 128 + hl * 8;
    #pragma unroll
    for (int ks = 0; ks < 8; ++ks)
      acc = mfma32(afr[ks], ldg8(wrow + ks * 16), acc);
    float bo = biasP[b * 384 + o0 + ln];
    #pragma unroll
    for (int r = 0; r < 16; ++r){
      int srow = s0 + rowmap(r, hl);
      qkvT[(size_t)(b * SS + srow) * 384 + o0 + ln] = f2bf(acc[r] + bo);
    }
  }
}

// ---------------- K3: 2x2x2 avg-pool of K,V -> MFMA-fragment-linear layout ----------------
// kfr/vfr layout: per (b,h,tile64): 4 call-blocks of 512 ushorts (1KB); k_attn lane L
// reads call-block base + L*8 ushorts (16B) -> perfectly coalesced 1KB per load.
// K call c (0=ka0,1=ka1,2=kb0,3=kb1): content K[m0 + 32*(c>>1) + (L&31)][(c&1)*16 + (L>>5)*8 + j]
// V call c: content V[L&31][m0 + c*16 + (L>>5)*8 + j]
__global__ __launch_bounds__(256) void k_pool(const ushort* __restrict__ qkvT,
                                              ushort* __restrict__ kfr, ushort* __restrict__ vfr){
  int bid = blockIdx.x;          // 216 = b*108 + h*27 + mt
  int mt = bid % 27;
  int h  = (bid / 27) & 3;
  int b  = bid / 108;
  int m0 = mt * 64;
  int t = threadIdx.x;
  int kl = t & 63, o = t >> 6;   // key-local 0..63, d-octet 0..3
  int m = m0 + kl;
  int h2 = m / 144; int rem = m - h2 * 144; int w2 = rem / 12; int d2 = rem - w2 * 12;
  int sb = h2 * 1152 + w2 * 48 + d2 * 2;
  const ushort* base = qkvT + (size_t)b * SS * 384 + 128 + h * 32 + o * 8;
  float ks[8] = {0,0,0,0,0,0,0,0}, vs[8] = {0,0,0,0,0,0,0,0};
  #pragma unroll
  for (int i = 0; i < 2; ++i)
    #pragma unroll
    for (int jj = 0; jj < 2; ++jj)
      #pragma unroll
      for (int kk = 0; kk < 2; ++kk){
        const ushort* row = base + (size_t)(sb + i * 576 + jj * 24 + kk) * 384;
        union { uint4 q; ushort us[8]; } K8, V8;
        K8.q = *reinterpret_cast<const uint4*>(row);        // K chunk
        V8.q = *reinterpret_cast<const uint4*>(row + 128);  // V chunk
        #pragma unroll
        for (int j = 0; j < 8; ++j){ ks[j] += bf2f(K8.us[j]); vs[j] += bf2f(V8.us[j]); }
      }
  // K: direct fragment-linear write (thread owns key x d-octet = one 16B fragment chunk)
  union { uint4 q; ushort us[8]; } KW;
  #pragma unroll
  for (int j = 0; j < 8; ++j) KW.us[j] = f2bf(ks[j] * 0.125f);
  int call = 2 * (kl >> 5) + (o >> 1);
  int lane = (kl & 31) + 32 * (o & 1);
  size_t kb_ = ((size_t)((b * 4 + h) * 27 + mt) * 4 + call) * 512 + lane * 8;
  *reinterpret_cast<uint4*>(&kfr[kb_]) = KW.q;
  // V: needs (d x key-octet) fragments -> transpose through LDS
  __shared__ ushort V_lds[32][72];
  #pragma unroll
  for (int j = 0; j < 8; ++j) V_lds[o * 8 + j][kl] = f2bf(vs[j] * 0.125f);
  __syncthreads();
  int d = t & 31, ko = t >> 5;   // d 0..31, key-octet 0..7
  uint4 vv = *reinterpret_cast<const uint4*>(&V_lds[d][ko * 8]);
  int c = ko >> 1, hl2 = ko & 1;
  int lane2 = d + 32 * hl2;
  size_t vb_ = ((size_t)((b * 4 + h) * 27 + mt) * 4 + c) * 512 + lane2 * 8;
  *reinterpret_cast<uint4*>(&vfr[vb_]) = vv;
}

// ---------------- K4: attention; all K/V loads fragment-linear (1KB coalesced),
// stateless softmax, l via ones-MFMA, permlane32_swap P-exchange, K dbuf ----------------
#define PVSTEP(Parr, i4, vf)                                         \
  {                                                                  \
    uint a0 = Parr[(i4) + 0], a1 = Parr[(i4) + 1];                   \
    uint b0 = Parr[(i4) + 2], b1 = Parr[(i4) + 3];                   \
    asm("v_permlane32_swap_b32 %0, %1" : "+v"(a0), "+v"(b0));        \
    asm("v_permlane32_swap_b32 %0, %1" : "+v"(a1), "+v"(b1));        \
    union { uint u[4]; bf16x8 b8; } pf;                              \
    pf.u[0] = a0; pf.u[1] = a1; pf.u[2] = b0; pf.u[3] = b1;          \
    oacc = mfma32(vf, pf.b8, oacc);                                  \
    lacc = mfma32(ones, pf.b8, lacc);                                \
  }

__global__ __launch_bounds__(128, 4) void k_attn(const ushort* __restrict__ qkvT, const ushort* __restrict__ kfr,
                                                 const ushort* __restrict__ vfr, ushort* __restrict__ Ot){
  int bid = blockIdx.x;           // 1728 = (b*4+h)*216 + st
  int st = bid % 216;
  int bh = bid / 216;
  int h = bh & 3, b = bh >> 2;
  int t = threadIdx.x, w = t >> 6, lane = t & 63, hl = lane >> 5, ln = lane & 31;
  int n = st * 64 + w * 32 + ln;
  const ushort* qb = qkvT + (size_t)(b * SS + n) * 384 + h * 32;
  bf16x8 qf0 = ldg8(qb + hl * 8);
  bf16x8 qf1 = ldg8(qb + 16 + hl * 8);
  const ushort* kbase = kfr + (size_t)(b * 4 + h) * 27 * 2048 + (size_t)lane * 8;
  const ushort* vbase = vfr + (size_t)(b * 4 + h) * 27 * 2048 + (size_t)lane * 8;
  union { ushort us[8]; bf16x8 b8; } one8;
  #pragma unroll
  for (int j = 0; j < 8; ++j) one8.us[j] = 0x3F80; // bf16 1.0
  bf16x8 ones = one8.b8;
  f32x16 oacc = {}, lacc = {};
  // preload K tile 0
  bf16x8 kc0 = ldg8(kbase), kc1 = ldg8(kbase + 512);
  bf16x8 kc2 = ldg8(kbase + 1024), kc3 = ldg8(kbase + 1536);
  for (int it = 0; it < 27; ++it){
    // V of current tile: issued well before PV use
    const ushort* vp = vbase + it * 2048;
    bf16x8 v0 = ldg8(vp), v1 = ldg8(vp + 512), v2 = ldg8(vp + 1024), v3 = ldg8(vp + 1536);
    // QK^T on current K
    f32x16 s0 = {}, s1 = {};
    s0 = mfma32(kc0, qf0, s0);
    s0 = mfma32(kc1, qf1, s0);
    s1 = mfma32(kc2, qf0, s1);
    s1 = mfma32(kc3, qf1, s1);
    // prefetch next K tile (wrap to 0 on last iter to keep addresses valid)
    int itn = it + 1; if (itn == 27) itn = 0;
    const ushort* kpn = kbase + itn * 2048;
    bf16x8 kn0 = ldg8(kpn), kn1 = ldg8(kpn + 512);
    bf16x8 kn2 = ldg8(kpn + 1024), kn3 = ldg8(kpn + 1536);
    // stateless softmax numerator: P = exp2(s) (scale*log2e folded into q)
    #pragma unroll
    for (int r = 0; r < 16; ++r) s0[r] = fexp2(s0[r]);
    #pragma unroll
    for (int r = 0; r < 16; ++r) s1[r] = fexp2(s1[r]);
    uint P0[8], P1[8];
    #pragma unroll
    for (int i = 0; i < 8; ++i) P0[i] = pk2(s0[2 * i], s0[2 * i + 1]);
    #pragma unroll
    for (int i = 0; i < 8; ++i) P1[i] = pk2(s1[2 * i], s1[2 * i + 1]);
    PVSTEP(P0, 0, v0)
    PVSTEP(P0, 4, v1)
    PVSTEP(P1, 0, v2)
    PVSTEP(P1, 4, v3)
    kc0 = kn0; kc1 = kn1; kc2 = kn2; kc3 = kn3;
  }
  float inv = 1.f / lacc[0];   // lacc rows all hold sum_k P[k][col]
  // transpose O fragment (rows=d, cols=n) -> Ot[s][c] via per-wave LDS tile
  __shared__ ushort T[2][32 * 40];
  ushort* Tw = T[w];
  #pragma unroll
  for (int r = 0; r < 16; ++r){
    int d = rowmap(r, hl);
    Tw[ln * 40 + d] = f2bf(oacc[r] * inv);
  }
  __syncthreads();
  #pragma unroll
  for (int it = 0; it < 2; ++it){
    int d0 = hl * 8 + it * 16;
    uint4 vv = *reinterpret_cast<const uint4*>(&Tw[ln * 40 + d0]);
    *reinterpret_cast<uint4*>(&Ot[(size_t)(b * SS + n) * 128 + h * 32 + d0]) = vv;
  }
}

// ---------------- K5: proj GEMM + bias + residual ----------------
__global__ __launch_bounds__(256) void k_proj(const ushort* __restrict__ Ot, const ushort* __restrict__ pw,
                                              const float* __restrict__ pb, const float* __restrict__ xres,
                                              float* __restrict__ out){
  int bid = blockIdx.x;          // 216 = b*108 + st
  int st = bid % 108;
  int b = bid / 108;
  int t = threadIdx.x, w = t >> 6, lane = t & 63, hl = lane >> 5, ln = lane & 31;
  int s0 = st * 128 + w * 32;
  int s = s0 + ln;
  const ushort* ob = Ot + (size_t)(b * SS + s) * 128 + hl * 8;
  bf16x8 bfr[8];
  #pragma unroll
  for (int ks = 0; ks < 8; ++ks) bfr[ks] = ldg8(ob + ks * 16);
  for (int ot = 0; ot < 4; ++ot){
    f32x16 acc = {};
    const ushort* arow = pw + (size_t)(ot * 32 + ln) * 128 + hl * 8;
    #pragma unroll
    for (int ks = 0; ks < 8; ++ks)
      acc = mfma32(ldg8(arow + ks * 16), bfr[ks], acc);
    #pragma unroll
    for (int r = 0; r < 16; ++r){
      int o = ot * 32 + rowmap(r, hl);
      size_t idx = (size_t)(b * 128 + o) * SS + s;
      out[idx] = acc[r] + pb[o] + xres[idx];
    }
  }
}

extern "C" void kernel_launch(void* const* d_in, const int* in_sizes, int n_in,
                              void* d_out, int out_size, void* d_ws, size_t ws_size,
                              hipStream_t stream){
  const float* x      = (const float*)d_in[0];
  const float* gn_w   = (const float*)d_in[1];
  const float* gn_b   = (const float*)d_in[2];
  const float* qkv_w  = (const float*)d_in[3];
  const float* qkv_b  = (const float*)d_in[4];
  const float* proj_w = (const float*)d_in[5];
  const float* proj_b = (const float*)d_in[6];
  float* out = (float*)d_out;
  char* ws = (char*)d_ws;

  float*  chsums = (float*) (ws + 0);          // 2048 B
  ushort* Wp     = (ushort*)(ws + 2048);       // 196608 B
  float*  biasP  = (float*) (ws + 198656);     // 3072 B
  ushort* pw     = (ushort*)(ws + 201728);     // 32768 B
  ushort* qkvT   = (ushort*)(ws + 234496);     // 21233664 B
  ushort* kfr    = (ushort*)(ws + 21468160);   // 884736 B (fragment-linear K)
  ushort* vfr    = (ushort*)(ws + 22352896);   // 884736 B (fragment-linear V)
  ushort* Ot     = (ushort*)(ws + 23237632);   // 7077888 B  (total ~30.3 MB)

  k_stats <<<256,  256, 0, stream>>>(x, chsums);
  k_params<<<4,    256, 0, stream>>>(chsums, gn_w, gn_b, qkv_w, qkv_b, proj_w, Wp, biasP, pw);
  k_qkv   <<<432,  256, 0, stream>>>(x, Wp, biasP, qkvT);
  k_pool  <<<216,  256, 0, stream>>>(qkvT, kfr, vfr);
  k_attn  <<<1728, 128, 0, stream>>>(qkvT, kfr, vfr, Ot);
  k_proj  <<<216,  256, 0, stream>>>(Ot, pw, proj_b, x, out);
}